// Round 8
// baseline (286.777 us; speedup 1.0000x reference)
//
#include <hip/hip_runtime.h>
#include <math.h>

// Problem constants
#define R_ 5
#define NN 68        // N_NODES == LATENT
#define KK 32        // neighbors per node
#define NL 3         // GCN layers
#define LAT 68
#define NSL 17               // nodes per wave slice (4 waves x 17 = 68)
#define ROWQ (NN / 4)        // 17 float4 per node row
#define NF4 ((NN * NN) / 4)  // 1156 float4 per output row
#define BBK2 16              // batches per K2 block
#define LSTR 344             // LDS row stride (floats) for K2, 16B-aligned

typedef float f32x4 __attribute__((ext_vector_type(4)));  // clang-native vec4
                                                          // (nontemporal-ok)

// ---------------- P1: densify GCN weights ----------------
// W'[m][n] = sum_{k: adj[n,k]==m} gw[n,k]  (exact rewrite of the gather)
__global__ __launch_bounds__(128) void densify_k(
    const int* __restrict__ adj, const float* __restrict__ gw,
    float* __restrict__ wd) {
  const int rl = blockIdx.x;  // r*NL + l in 0..14
  const int t = threadIdx.x;
  __shared__ float col[NN][NN + 4];
  for (int i = t; i < NN * (NN + 4); i += 128) (&col[0][0])[i] = 0.0f;
  __syncthreads();
  if (t < NN) {
    const int n = t;  // thread owns column n -> no races
    const int* ar = adj + n * KK;
    const float* wr = gw + ((size_t)rl * NN + n) * KK;
    for (int k = 0; k < KK; ++k) col[ar[k]][n] += wr[k];
  }
  __syncthreads();
  float* wout = wd + (size_t)rl * NN * NN;  // [m][n], n contiguous
  for (int i = t; i < NN * NN; i += 128) {
    const int m = i / NN, n = i - m * NN;
    wout[i] = col[m][n];
  }
}

// ---------------- P2: transpose z -> zT[l][b] ----------------
__global__ __launch_bounds__(256) void ztr_k(const float* __restrict__ z,
                                             float* __restrict__ zT, int B) {
  const int t = threadIdx.x;
  const int b0 = blockIdx.x * 64;
  __shared__ float zls[64][LAT + 1];  // +1: stride 69 -> conflict-free both ways
  for (int idx = t; idx < 64 * ROWQ; idx += 256) {
    const int row = idx / ROWQ, q = idx - row * ROWQ;
    const float4 v =
        *reinterpret_cast<const float4*>(z + (size_t)(b0 + row) * LAT + 4 * q);
    zls[row][4 * q + 0] = v.x;
    zls[row][4 * q + 1] = v.y;
    zls[row][4 * q + 2] = v.z;
    zls[row][4 * q + 3] = v.w;
  }
  __syncthreads();
  for (int idx = t; idx < LAT * 64; idx += 256) {
    const int l = idx >> 6, bb = idx & 63;
    zT[(size_t)l * B + b0 + bb] = zls[bb][l];
  }
}

// ---------------- K1: GEMM-chain, 4 waves x 17-node slices ----------------
// (unchanged — scalar s_load weight path, 20 waves/CU)
__global__ __launch_bounds__(256) void chain_k(
    const float* __restrict__ zT, const float* __restrict__ fc_w,
    const float* __restrict__ fc_b, const float* __restrict__ wd,
    const float* __restrict__ gb, float* __restrict__ X, int B, int nb) {
  const int t = threadIdx.x;
  const int lane = t & 63;
  const int w = __builtin_amdgcn_readfirstlane(t >> 6);
  const int n0 = w * NSL;  // first node of this wave's slice (wave-uniform)
  const int r = blockIdx.x / nb;
  const int b0 = (blockIdx.x - r * nb) * 64;

  __shared__ float xs[NN][64];  // 17.4 KB; z, then x, per stage

  for (int idx = t; idx < NN * 64; idx += 256) {
    const int m = idx >> 6;
    xs[m][idx & 63] = zT[(size_t)m * B + b0 + (idx & 63)];
  }
  __syncthreads();

  float acc[NSL];

#pragma unroll 1
  for (int stage = 0; stage < 1 + NL; ++stage) {
    const float* wb = (stage == 0) ? fc_w + (size_t)r * LAT * NN
                                   : wd + (size_t)(r * NL + stage - 1) * NN * NN;
    const float* bias = (stage == 0) ? fc_b + r * NN
                                     : gb + (size_t)(r * NL + stage - 1) * NN;
#pragma unroll
    for (int j = 0; j < NSL; ++j) acc[j] = bias[n0 + j];  // uniform -> s_load

#pragma unroll 2
    for (int m = 0; m < NN; ++m) {
      const float xm = xs[m][lane];          // stride-64, conflict-free
      const float* wr = wb + m * NN + n0;    // wave-uniform -> s_load chunk
#pragma unroll
      for (int j = 0; j < NSL; ++j) acc[j] = fmaf(xm, wr[j], acc[j]);
    }
    if (stage > 0) {
#pragma unroll
      for (int j = 0; j < NSL; ++j)
        acc[j] = 1.0f / (1.0f + __expf(-acc[j]));
    }
    if (stage < NL) {
      __syncthreads();
#pragma unroll
      for (int j = 0; j < NSL; ++j) xs[n0 + j][lane] = acc[j];
      __syncthreads();
    }
  }

  float* Xb = X + ((size_t)r * NN + n0) * B + b0 + lane;
#pragma unroll
  for (int j = 0; j < NSL; ++j) Xb[(size_t)j * B] = acc[j];
}

// ---------------- K2: outer product + store, register-tiled ----------------
// Lane -> (bb, column-group c). xj4[r] preloaded ONCE (5 b128); i marched in
// 4-row groups with one broadcast b128 per r -> ~40x less LDS traffic than
// the flat version. Stores: 16 consecutive f4 per (bb,i) = 256B runs, nt-hint
// (out is never re-read). Column 16 (68=16*4+4) via a small flat edge loop.
__global__ __launch_bounds__(256) void outer_k(const float* __restrict__ X,
                                               float* __restrict__ out, int B) {
  const int t = threadIdx.x;
  const int b0 = blockIdx.x * BBK2;
  __shared__ float xls[BBK2 * LSTR];

  // stage X[rn][b0..b0+15] -> xls[bb][rn]; reads are exact 64B lines
  for (int idx = t; idx < R_ * NN * BBK2; idx += 256) {
    const int rn = idx >> 4, bb = idx & (BBK2 - 1);
    xls[bb * LSTR + rn] = X[(size_t)rn * B + b0 + bb];
  }
  __syncthreads();

  const int lane = t & 63;
  const int wv = t >> 6;
  const int bb = wv * 4 + (lane >> 4);  // 0..15
  const int c  = lane & 15;             // f4-column 0..15
  const float* xb = &xls[bb * LSTR];

  float4 xj[R_];
#pragma unroll
  for (int r = 0; r < R_; ++r)
    xj[r] = *reinterpret_cast<const float4*>(xb + r * NN + 4 * c);

  f32x4* obase = reinterpret_cast<f32x4*>(out) + (size_t)(b0 + bb) * NF4 + c;
#pragma unroll 2
  for (int g = 0; g < 17; ++g) {       // rows i = 4g..4g+3
    float4 xi[R_];
#pragma unroll
    for (int r = 0; r < R_; ++r)
      xi[r] = *reinterpret_cast<const float4*>(xb + r * NN + 4 * g);  // bcast
#pragma unroll
    for (int k = 0; k < 4; ++k) {
      float4 a = make_float4(0.f, 0.f, 0.f, 0.f);
#pragma unroll
      for (int r = 0; r < R_; ++r) {
        const float s = reinterpret_cast<const float*>(&xi[r])[k];  // static k
        a.x = fmaf(s, xj[r].x, a.x);
        a.y = fmaf(s, xj[r].y, a.y);
        a.z = fmaf(s, xj[r].z, a.z);
        a.w = fmaf(s, xj[r].w, a.w);
      }
      f32x4 av = {a.x, a.y, a.z, a.w};
      __builtin_nontemporal_store(av, obase + (size_t)(4 * g + k) * ROWQ);
    }
  }

  // edge: f4-column 16 (floats 64..67) for all (bb, i)
  for (int fg = t; fg < BBK2 * NN; fg += 256) {
    const int bb2 = fg / NN, i = fg - bb2 * NN;
    const float* xb2 = &xls[bb2 * LSTR];
    float4 a = make_float4(0.f, 0.f, 0.f, 0.f);
#pragma unroll
    for (int r = 0; r < R_; ++r) {
      const float s = xb2[r * NN + i];
      const float4 x4 = *reinterpret_cast<const float4*>(xb2 + r * NN + 64);
      a.x = fmaf(s, x4.x, a.x);
      a.y = fmaf(s, x4.y, a.y);
      a.z = fmaf(s, x4.z, a.z);
      a.w = fmaf(s, x4.w, a.w);
    }
    f32x4 av = {a.x, a.y, a.z, a.w};
    __builtin_nontemporal_store(
        av, reinterpret_cast<f32x4*>(out) + (size_t)(b0 + bb2) * NF4 +
                (size_t)i * ROWQ + 16);
  }
}

extern "C" void kernel_launch(void* const* d_in, const int* in_sizes, int n_in,
                              void* d_out, int out_size, void* d_ws, size_t ws_size,
                              hipStream_t stream) {
  const float* z    = (const float*)d_in[0];  // (16384, 68)
  const int*   adj  = (const int*)  d_in[1];  // (68, 32)
  const float* fc_w = (const float*)d_in[2];  // (5, 68, 68)
  const float* fc_b = (const float*)d_in[3];  // (5, 68)
  const float* gw   = (const float*)d_in[4];  // (5, 3, 68, 32)
  const float* gb   = (const float*)d_in[5];  // (5, 3, 68)
  float* out = (float*)d_out;                 // (16384, 4624)

  const int B = in_sizes[0] / LAT;            // 16384
  // ws layout (f32): wd[15*68*68] | zT[68*B] | X[340*B]  (~27.1 MB total)
  float* wd = (float*)d_ws;
  float* zT = wd + R_ * NL * NN * NN;
  float* X  = zT + (size_t)LAT * B;

  const int nb = B / 64;                      // 256 batch-groups

  densify_k<<<R_ * NL, 128, 0, stream>>>(adj, gw, wd);
  ztr_k<<<B / 64, 256, 0, stream>>>(z, zT, B);
  chain_k<<<R_ * nb, 256, 0, stream>>>(zT, fc_w, fc_b, wd, gb, X, B, nb);
  outer_k<<<B / BBK2, 256, 0, stream>>>(X, out, B);
}

// Round 9
// 147.107 us; speedup vs baseline: 1.9495x; 1.9495x over previous
//
#include <hip/hip_runtime.h>
#include <math.h>

// Problem constants
#define R_ 5
#define NN 68        // N_NODES == LATENT
#define KK 32        // neighbors per node
#define NL 3         // GCN layers
#define LAT 68
#define NSL 17               // nodes per wave slice (4 waves x 17 = 68)
#define ROWQ (NN / 4)        // 17 float4 per node row
#define NF4 ((NN * NN) / 4)  // 1156 float4 per output row
#define BBK2 16              // batches per K2 block
#define LSTR 344             // LDS row stride (floats) for K2, 16B-aligned

// ---------------- P1: densify GCN weights ----------------
// W'[m][n] = sum_{k: adj[n,k]==m} gw[n,k]  (exact rewrite of the gather)
__global__ __launch_bounds__(128) void densify_k(
    const int* __restrict__ adj, const float* __restrict__ gw,
    float* __restrict__ wd) {
  const int rl = blockIdx.x;  // r*NL + l in 0..14
  const int t = threadIdx.x;
  __shared__ float col[NN][NN + 4];
  for (int i = t; i < NN * (NN + 4); i += 128) (&col[0][0])[i] = 0.0f;
  __syncthreads();
  if (t < NN) {
    const int n = t;  // thread owns column n -> no races
    const int* ar = adj + n * KK;
    const float* wr = gw + ((size_t)rl * NN + n) * KK;
    for (int k = 0; k < KK; ++k) col[ar[k]][n] += wr[k];
  }
  __syncthreads();
  float* wout = wd + (size_t)rl * NN * NN;  // [m][n], n contiguous
  for (int i = t; i < NN * NN; i += 128) {
    const int m = i / NN, n = i - m * NN;
    wout[i] = col[m][n];
  }
}

// ---------------- P2: transpose z -> zT[l][b] ----------------
__global__ __launch_bounds__(256) void ztr_k(const float* __restrict__ z,
                                             float* __restrict__ zT, int B) {
  const int t = threadIdx.x;
  const int b0 = blockIdx.x * 64;
  __shared__ float zls[64][LAT + 1];  // +1: stride 69 -> conflict-free both ways
  for (int idx = t; idx < 64 * ROWQ; idx += 256) {
    const int row = idx / ROWQ, q = idx - row * ROWQ;
    const float4 v =
        *reinterpret_cast<const float4*>(z + (size_t)(b0 + row) * LAT + 4 * q);
    zls[row][4 * q + 0] = v.x;
    zls[row][4 * q + 1] = v.y;
    zls[row][4 * q + 2] = v.z;
    zls[row][4 * q + 3] = v.w;
  }
  __syncthreads();
  for (int idx = t; idx < LAT * 64; idx += 256) {
    const int l = idx >> 6, bb = idx & 63;
    zT[(size_t)l * B + b0 + bb] = zls[bb][l];
  }
}

// ---------------- K1: GEMM-chain, 4 waves x 17-node slices ----------------
// (unchanged — scalar s_load weight path, 20 waves/CU)
__global__ __launch_bounds__(256) void chain_k(
    const float* __restrict__ zT, const float* __restrict__ fc_w,
    const float* __restrict__ fc_b, const float* __restrict__ wd,
    const float* __restrict__ gb, float* __restrict__ X, int B, int nb) {
  const int t = threadIdx.x;
  const int lane = t & 63;
  const int w = __builtin_amdgcn_readfirstlane(t >> 6);
  const int n0 = w * NSL;  // first node of this wave's slice (wave-uniform)
  const int r = blockIdx.x / nb;
  const int b0 = (blockIdx.x - r * nb) * 64;

  __shared__ float xs[NN][64];  // 17.4 KB; z, then x, per stage

  for (int idx = t; idx < NN * 64; idx += 256) {
    const int m = idx >> 6;
    xs[m][idx & 63] = zT[(size_t)m * B + b0 + (idx & 63)];
  }
  __syncthreads();

  float acc[NSL];

#pragma unroll 1
  for (int stage = 0; stage < 1 + NL; ++stage) {
    const float* wb = (stage == 0) ? fc_w + (size_t)r * LAT * NN
                                   : wd + (size_t)(r * NL + stage - 1) * NN * NN;
    const float* bias = (stage == 0) ? fc_b + r * NN
                                     : gb + (size_t)(r * NL + stage - 1) * NN;
#pragma unroll
    for (int j = 0; j < NSL; ++j) acc[j] = bias[n0 + j];  // uniform -> s_load

#pragma unroll 2
    for (int m = 0; m < NN; ++m) {
      const float xm = xs[m][lane];          // stride-64, conflict-free
      const float* wr = wb + m * NN + n0;    // wave-uniform -> s_load chunk
#pragma unroll
      for (int j = 0; j < NSL; ++j) acc[j] = fmaf(xm, wr[j], acc[j]);
    }
    if (stage > 0) {
#pragma unroll
      for (int j = 0; j < NSL; ++j)
        acc[j] = 1.0f / (1.0f + __expf(-acc[j]));
    }
    if (stage < NL) {
      __syncthreads();
#pragma unroll
      for (int j = 0; j < NSL; ++j) xs[n0 + j][lane] = acc[j];
      __syncthreads();
    }
  }

  float* Xb = X + ((size_t)r * NN + n0) * B + b0 + lane;
#pragma unroll
  for (int j = 0; j < NSL; ++j) Xb[(size_t)j * B] = acc[j];
}

// ---------------- K2: outer product, reg-tiled compute + LDS-staged store ---
// Compute keeps v8's register reuse: lane -> (bb = wv*4+lane>>4, c = lane&15);
// xj[r] preloaded once, xi[r] is one broadcast b128 per r per 4-row group.
// Results for each (4 rows x 16 batches x 68 cols) chunk go to obuf in LDS;
// after a barrier the chunk is flat-copied: consecutive lanes = consecutive
// f4, 1088B contiguous per batch, batch bases 64B-aligned (18496=289*64) ->
// every HBM line fully written (fixes v8's +24% WRITE_SIZE partial lines).
__global__ __launch_bounds__(256) void outer_k(const float* __restrict__ X,
                                               float* __restrict__ out, int B) {
  const int t = threadIdx.x;
  const int b0 = blockIdx.x * BBK2;
  __shared__ float xls[BBK2 * LSTR];   // 22.0 KB
  __shared__ float obuf[BBK2][4][NN];  // 17.4 KB chunk: [bb][i&3][col]

  // stage X[rn][b0..b0+15] -> xls[bb][rn]
  for (int idx = t; idx < R_ * NN * BBK2; idx += 256) {
    const int rn = idx >> 4, bb = idx & (BBK2 - 1);
    xls[bb * LSTR + rn] = X[(size_t)rn * B + b0 + bb];
  }
  __syncthreads();

  const int lane = t & 63;
  const int wv = t >> 6;
  const int bb = wv * 4 + (lane >> 4);  // 0..15
  const int c = lane & 15;              // f4-col 0..15; lane c==0 also col 16
  const float* xb = &xls[bb * LSTR];

  float4 xj[R_], xj16[R_];
#pragma unroll
  for (int r = 0; r < R_; ++r)
    xj[r] = *reinterpret_cast<const float4*>(xb + r * NN + 4 * c);
#pragma unroll
  for (int r = 0; r < R_; ++r)
    xj16[r] = *reinterpret_cast<const float4*>(xb + r * NN + 64);

#pragma unroll 1
  for (int g = 0; g < 17; ++g) {  // rows i = 4g..4g+3
    float4 xi[R_];
#pragma unroll
    for (int r = 0; r < R_; ++r)
      xi[r] = *reinterpret_cast<const float4*>(xb + r * NN + 4 * g);  // bcast
#pragma unroll
    for (int k = 0; k < 4; ++k) {
      float4 a = make_float4(0.f, 0.f, 0.f, 0.f);
#pragma unroll
      for (int r = 0; r < R_; ++r) {
        const float s = reinterpret_cast<const float*>(&xi[r])[k];  // static k
        a.x = fmaf(s, xj[r].x, a.x);
        a.y = fmaf(s, xj[r].y, a.y);
        a.z = fmaf(s, xj[r].z, a.z);
        a.w = fmaf(s, xj[r].w, a.w);
      }
      *reinterpret_cast<float4*>(&obuf[bb][k][4 * c]) = a;
      if (c == 0) {  // edge f4-column 16 (cols 64..67)
        float4 e = make_float4(0.f, 0.f, 0.f, 0.f);
#pragma unroll
        for (int r = 0; r < R_; ++r) {
          const float s = reinterpret_cast<const float*>(&xi[r])[k];
          e.x = fmaf(s, xj16[r].x, e.x);
          e.y = fmaf(s, xj16[r].y, e.y);
          e.z = fmaf(s, xj16[r].z, e.z);
          e.w = fmaf(s, xj16[r].w, e.w);
        }
        *reinterpret_cast<float4*>(&obuf[bb][k][64]) = e;
      }
    }
    __syncthreads();  // chunk complete

    // flat coalesced copy: 1088 f4; LDS side is contiguous 16B per lane
    const float4* ob4 = reinterpret_cast<const float4*>(&obuf[0][0][0]);
    for (int fg = t; fg < BBK2 * NN; fg += 256) {
      const int bb2 = fg / NN;            // batch
      const int rem = fg - bb2 * NN;      // i*17+q within chunk
      const int i2 = rem / ROWQ, q2 = rem - i2 * ROWQ;
      reinterpret_cast<float4*>(out)[(size_t)(b0 + bb2) * NF4 +
                                     (size_t)(4 * g + i2) * ROWQ + q2] =
          ob4[fg];
    }
    __syncthreads();  // obuf consumed before next g overwrites
  }
}

extern "C" void kernel_launch(void* const* d_in, const int* in_sizes, int n_in,
                              void* d_out, int out_size, void* d_ws, size_t ws_size,
                              hipStream_t stream) {
  const float* z    = (const float*)d_in[0];  // (16384, 68)
  const int*   adj  = (const int*)  d_in[1];  // (68, 32)
  const float* fc_w = (const float*)d_in[2];  // (5, 68, 68)
  const float* fc_b = (const float*)d_in[3];  // (5, 68)
  const float* gw   = (const float*)d_in[4];  // (5, 3, 68, 32)
  const float* gb   = (const float*)d_in[5];  // (5, 3, 68)
  float* out = (float*)d_out;                 // (16384, 4624)

  const int B = in_sizes[0] / LAT;            // 16384
  // ws layout (f32): wd[15*68*68] | zT[68*B] | X[340*B]  (~27.1 MB total)
  float* wd = (float*)d_ws;
  float* zT = wd + R_ * NL * NN * NN;
  float* X  = zT + (size_t)LAT * B;

  const int nb = B / 64;                      // 256 batch-groups

  densify_k<<<R_ * NL, 128, 0, stream>>>(adj, gw, wd);
  ztr_k<<<B / 64, 256, 0, stream>>>(z, zT, B);
  chain_k<<<R_ * nb, 256, 0, stream>>>(zT, fc_w, fc_b, wd, gb, X, B, nb);
  outer_k<<<B / BBK2, 256, 0, stream>>>(X, out, B);
}